// Round 18
// baseline (300.374 us; speedup 1.0000x reference)
//
#include <hip/hip_runtime.h>

#define NROWS 524288
#define NCH 128
#define GSTR 40

typedef __attribute__((ext_vector_type(8))) short bf16x8;
typedef __attribute__((ext_vector_type(4))) float f32x4;

// barrier WITHOUT vmcnt drain: LDS ordering only (T4-lite).
#define BARRIER_ND() asm volatile("s_waitcnt lgkmcnt(0)\ns_barrier" ::: "memory")

static __device__ __forceinline__ unsigned short f2bf_rne(float f) {
    unsigned u = __float_as_uint(f);
    return (unsigned short)((u + 0x7FFFu + ((u >> 16) & 1u)) >> 16);
}

// Channel row layout: data starts at ((c>>3)&1)*8 u16 within the 40-u16 row
// (pad as bank-offset: 32 distinct write banks across wave64 = 2-way = free).
static __device__ __forceinline__ bf16x8 ldfrag(const unsigned short* base, int c, int s0) {
    int m = (c >> 3) & 12;
    return *(const bf16x8*)(base + c * GSTR + (((c >> 3) & 1) << 3) + 2 * (s0 ^ m));
}

// ---------------------------------------------------------------------------
// k_gram (R15-proven): G2 = H^T H + H^T (2L); (256,4); no-drain barriers.
// ---------------------------------------------------------------------------
#define PACKW1(B, c, x0, x1, csacc) do {                                      \
    unsigned u0 = __float_as_uint(x0), u1 = __float_as_uint(x1);              \
    unsigned packH = (u0 >> 16) | (u1 & 0xFFFF0000u);                         \
    float l0_ = 2.0f * ((x0) - __uint_as_float(u0 & 0xFFFF0000u));            \
    float l1_ = 2.0f * ((x1) - __uint_as_float(u1 & 0xFFFF0000u));            \
    unsigned packL = (unsigned)f2bf_rne(l0_) | ((unsigned)f2bf_rne(l1_) << 16); \
    int idx_ = (c) * GSTR + ((cg & 1) << 3) + 2 * (p ^ (cg & 12));            \
    *(unsigned*)&XT[B][0][idx_] = packH;                                      \
    *(unsigned*)&XT[B][1][idx_] = packL;                                      \
    csacc += (x0) + (x1);                                                     \
} while (0)

#define LOADR(ci, r0, r1, r2, r3) do {                                        \
    const float4* s4_ = (const float4*)x + ((size_t)(ci) * 32 + 2 * p) * 32 + cg * 2; \
    r0 = s4_[0]; r1 = s4_[1]; r2 = s4_[32]; r3 = s4_[33];                     \
} while (0)

#define PACKALL(B, r0, r1, r2, r3) do {                                       \
    PACKW1(B, cg * 8 + 0, r0.x, r2.x, cs0);                                   \
    PACKW1(B, cg * 8 + 1, r0.y, r2.y, cs1);                                   \
    PACKW1(B, cg * 8 + 2, r0.z, r2.z, cs2);                                   \
    PACKW1(B, cg * 8 + 3, r0.w, r2.w, cs3);                                   \
    PACKW1(B, cg * 8 + 4, r1.x, r3.x, cs4);                                   \
    PACKW1(B, cg * 8 + 5, r1.y, r3.y, cs5);                                   \
    PACKW1(B, cg * 8 + 6, r1.z, r3.z, cs6);                                   \
    PACKW1(B, cg * 8 + 7, r1.w, r3.w, cs7);                                   \
} while (0)

#define MFMA_STEP(B) do {                                                     \
    const unsigned short* Xh = &XT[B][0][0];                                  \
    const unsigned short* Xl = &XT[B][1][0];                                  \
    bf16x8 ah0 = ldfrag(Xh, (2 * w + 0) * 16 + lc, ls);                       \
    bf16x8 ah1 = ldfrag(Xh, (2 * w + 1) * 16 + lc, ls);                       \
    _Pragma("unroll")                                                         \
    for (int tj = 0; tj < 8; ++tj) {                                          \
        bf16x8 bh = ldfrag(Xh, tj * 16 + lc, ls);                             \
        bf16x8 bl = ldfrag(Xl, tj * 16 + lc, ls);                             \
        acc[0][tj] = __builtin_amdgcn_mfma_f32_16x16x32_bf16(ah0, bh, acc[0][tj], 0, 0, 0); \
        acc[0][tj] = __builtin_amdgcn_mfma_f32_16x16x32_bf16(ah0, bl, acc[0][tj], 0, 0, 0); \
        acc[1][tj] = __builtin_amdgcn_mfma_f32_16x16x32_bf16(ah1, bh, acc[1][tj], 0, 0, 0); \
        acc[1][tj] = __builtin_amdgcn_mfma_f32_16x16x32_bf16(ah1, bl, acc[1][tj], 0, 0, 0); \
    }                                                                         \
} while (0)

template <int STORE>
__global__ __launch_bounds__(256, 4) void k_gram(const float* __restrict__ x,
                                                 float* __restrict__ part,
                                                 float* __restrict__ colpart,
                                                 float* __restrict__ gram,
                                                 float* __restrict__ colsum,
                                                 int cpb) {
    __shared__ __align__(16) unsigned short XT[2][2][128 * GSTR];  // [buf][hi/lo]
    const int tid = threadIdx.x;
    const int w = tid >> 6;
    const int l = tid & 63;
    const int lc = l & 15;
    const int ls = (l >> 4) * 4;
    const int p = tid >> 4;          // row-pair (rows 2p,2p+1 of chunk)
    const int cg = tid & 15;         // channel-group (8 ch), lane-minor

    f32x4 acc[2][8];
#pragma unroll
    for (int a = 0; a < 2; ++a)
#pragma unroll
        for (int t = 0; t < 8; ++t) acc[a][t] = (f32x4){0.f, 0.f, 0.f, 0.f};
    float cs0 = 0.f, cs1 = 0.f, cs2 = 0.f, cs3 = 0.f;
    float cs4 = 0.f, cs5 = 0.f, cs6 = 0.f, cs7 = 0.f;

    const int c0 = blockIdx.x * cpb;
    float4 a0, a1, a2, a3, b0, b1, b2, b3;

    LOADR(c0 + 0, a0, a1, a2, a3);
    LOADR(c0 + 1, b0, b1, b2, b3);
    PACKALL(0, a0, a1, a2, a3);
    BARRIER_ND();

#pragma unroll 1
    for (int t = 0; t < cpb; t += 2) {
        MFMA_STEP(0);                         // chunk t
        PACKALL(1, b0, b1, b2, b3);           // chunk t+1 -> LDS[1]
        if (t + 2 < cpb) LOADR(c0 + t + 2, a0, a1, a2, a3);
        BARRIER_ND();
        MFMA_STEP(1);                         // chunk t+1
        if (t + 2 < cpb) {
            PACKALL(0, a0, a1, a2, a3);       // chunk t+2 -> LDS[0]
            if (t + 3 < cpb) LOADR(c0 + t + 3, b0, b1, b2, b3);
            BARRIER_ND();
        }
    }

    // intra-block colsum reduction (reuse XT as float LDS)
    __syncthreads();
    float* cls = (float*)&XT[0][0][0];        // 128 ch x 16 pairs
    cls[(cg * 8 + 0) * 16 + p] = cs0;
    cls[(cg * 8 + 1) * 16 + p] = cs1;
    cls[(cg * 8 + 2) * 16 + p] = cs2;
    cls[(cg * 8 + 3) * 16 + p] = cs3;
    cls[(cg * 8 + 4) * 16 + p] = cs4;
    cls[(cg * 8 + 5) * 16 + p] = cs5;
    cls[(cg * 8 + 6) * 16 + p] = cs6;
    cls[(cg * 8 + 7) * 16 + p] = cs7;
    __syncthreads();
    float csr = 0.f;
    if (tid < 128) {
#pragma unroll
        for (int pp = 0; pp < 16; ++pp) csr += cls[tid * 16 + pp];
    }

    if (STORE) {
        float* pb = part + (size_t)blockIdx.x * 16384;
#pragma unroll
        for (int a = 0; a < 2; ++a)
#pragma unroll
            for (int tj = 0; tj < 8; ++tj)
#pragma unroll
                for (int q = 0; q < 4; ++q) {
                    int row = (2 * w + a) * 16 + (l >> 4) * 4 + q;
                    int col = tj * 16 + lc;
                    pb[row * NCH + col] = acc[a][tj][q];
                }
        if (tid < 128) colpart[blockIdx.x * 128 + tid] = csr;
    } else {
#pragma unroll
        for (int a = 0; a < 2; ++a)
#pragma unroll
            for (int tj = 0; tj < 8; ++tj)
#pragma unroll
                for (int q = 0; q < 4; ++q) {
                    int row = (2 * w + a) * 16 + (l >> 4) * 4 + q;
                    int col = tj * 16 + lc;
                    atomicAdd(&gram[row * NCH + col], acc[a][tj][q]);
                }
        if (tid < 128) atomicAdd(&colsum[tid], csr);
    }
}

// ---------------------------------------------------------------------------
// k_reduce1 (R7-proven): stage-1 tree fold of per-block partials.
// ---------------------------------------------------------------------------
__global__ __launch_bounds__(256) void k_reduce1(const float* __restrict__ part,
                                                 const float* __restrict__ colpart,
                                                 float* __restrict__ part2,
                                                 float* __restrict__ col2,
                                                 int NG) {
    const int b = blockIdx.x;
    if (b < 16 * NG) {
        const int g = b >> 4;
        const int sl = b & 15;
        const int e4 = sl * 1024 + threadIdx.x * 4;
        const float* p0 = part + (size_t)g * 32 * 16384 + e4;
        float4 s = {0.f, 0.f, 0.f, 0.f};
#pragma unroll
        for (int k = 0; k < 32; ++k) {
            float4 v = *(const float4*)(p0 + (size_t)k * 16384);
            s.x += v.x; s.y += v.y; s.z += v.z; s.w += v.w;
        }
        *(float4*)(part2 + (size_t)g * 16384 + e4) = s;
    } else {
        const int g = b - 16 * NG;
        if (threadIdx.x < 128) {
            const float* c0 = colpart + g * 32 * 128 + threadIdx.x;
            float s = 0.f;
#pragma unroll
            for (int k = 0; k < 32; ++k) s += c0[k * 128];
            col2[g * 128 + threadIdx.x] = s;
        }
    }
}

// ---------------------------------------------------------------------------
// k_chol: stage-2 fold MERGED in (reads part2/col2 directly, NG>0; legacy
// gram/colsum path when NG==0).  Block 0 = fold + 4-pivot blocked
// Gauss-Jordan; blocks 1..255 = fold col2 -> m, convert x -> swizzled bf16
// xn tiles (xbf) under chol's shadow.
// ---------------------------------------------------------------------------
__global__ __launch_bounds__(1024) void k_chol(const float* __restrict__ part2,
                                               const float* __restrict__ col2,
                                               const float* __restrict__ gram,
                                               const float* __restrict__ colsum,
                                               float* __restrict__ Wout,
                                               float* __restrict__ mout,
                                               const float* __restrict__ x,
                                               unsigned short* __restrict__ xbf,
                                               int NG) {
    if (blockIdx.x != 0) {
        __shared__ float msh[128];
        if (threadIdx.x < 128) {
            float s = 0.f;
            for (int g = 0; g < NG; ++g) s += col2[g * 128 + threadIdx.x];
            msh[threadIdx.x] = s * (1.0f / (float)NROWS);
        }
        __syncthreads();
        const size_t stride = (size_t)(gridDim.x - 1) * 1024;
        const size_t total = (size_t)(NROWS / 128) * 4096;   // 16.8M fragments
        for (size_t f = (size_t)(blockIdx.x - 1) * 1024 + threadIdx.x; f < total; f += stride) {
            int tile = (int)(f >> 12);
            int within = (int)(f & 4095);
            int r = within >> 5, i4 = within & 31;
            float4 vx = *(const float4*)&x[((size_t)tile * 128 + r) * 128 + i4 * 4];
            float4 mv = *(const float4*)&msh[i4 * 4];
            unsigned b0 = f2bf_rne(vx.x - mv.x);
            unsigned b1 = f2bf_rne(vx.y - mv.y);
            unsigned b2 = f2bf_rne(vx.z - mv.z);
            unsigned b3 = f2bf_rne(vx.w - mv.w);
            size_t d8 = (size_t)tile * 4096 + r * 32 + (((i4 >> 1) ^ (r & 15)) << 1) + (i4 & 1);
            ((uint2*)xbf)[d8] = make_uint2(b0 | (b1 << 16), b2 | (b3 << 16));
        }
        return;
    }

    __shared__ float C[128][264];                    // [0..127]=B, [128..255]=A
    __shared__ __align__(16) float Praw[2][4][264];  // double-buffered raw pivot rows
    __shared__ float m[128];
    __shared__ float dsq[128];
    const int tid = threadIdx.x;
    const int rs = tid >> 5;        // rowslot 0..31
    const int cs = tid & 31;        // colslot 0..31

    if (NG > 0) {
        // ---- stage-2 fold of part2 into raw A (C[i][128+j]) ----
        f32x4 f0 = {0,0,0,0}, f1 = {0,0,0,0}, f2 = {0,0,0,0}, f3 = {0,0,0,0};
        const f32x4* p24 = (const f32x4*)part2;
        for (int g = 0; g < NG; ++g) {
            const f32x4* pg = p24 + (size_t)g * 4096;
            f32x4 v0 = pg[tid], v1 = pg[tid + 1024], v2 = pg[tid + 2048], v3 = pg[tid + 3072];
            f0 += v0; f1 += v1; f2 += v2; f3 += v3;
        }
#define WRRAW(fk, k) do {                                                     \
        int e0 = (tid + (k) * 1024) * 4;                                      \
        int i_ = e0 >> 7, j_ = e0 & 127;                                      \
        *(f32x4*)&C[i_][128 + j_] = fk;                                       \
} while (0)
        WRRAW(f0, 0); WRRAW(f1, 1); WRRAW(f2, 2); WRRAW(f3, 3);
#undef WRRAW
        __syncthreads();
        if (tid < 128) {
            float s = 0.f;
            for (int g = 0; g < NG; ++g) s += col2[g * 128 + tid];
            m[tid] = s * (1.0f / (float)NROWS);
            mout[tid] = m[tid];
        }
        // symmetrize: read both (i,j),(j,i) into regs, barrier, write
        float rv[16];
#pragma unroll
        for (int k = 0; k < 4; ++k) {
            int e0 = (tid + k * 1024) * 4;
            int i_ = e0 >> 7, j0 = e0 & 127;
#pragma unroll
            for (int c = 0; c < 4; ++c)
                rv[k * 4 + c] = 0.5f * (C[i_][128 + j0 + c] + C[j0 + c][128 + i_]);
        }
        __syncthreads();
#pragma unroll
        for (int k = 0; k < 4; ++k) {
            int e0 = (tid + k * 1024) * 4;
            int i_ = e0 >> 7, j0 = e0 & 127;
#pragma unroll
            for (int c = 0; c < 4; ++c) {
                int j_ = j0 + c;
                C[i_][128 + j_] = (rv[k * 4 + c] - (float)NROWS * m[i_] * m[j_]) * (1.0f / (float)(NROWS - 1));
                C[i_][j_] = (i_ == j_) ? 1.0f : 0.0f;
            }
        }
        __syncthreads();
    } else {
        if (tid < 128) {
            m[tid] = colsum[tid] * (1.0f / (float)NROWS);
            mout[tid] = m[tid];
        }
        __syncthreads();
        for (int idx = tid; idx < 128 * 128; idx += 1024) {
            int i = idx >> 7, j = idx & 127;
            float g = 0.5f * (gram[i * NCH + j] + gram[j * NCH + i]);
            C[i][128 + j] = (g - (float)NROWS * m[i] * m[j]) * (1.0f / (float)(NROWS - 1));
            C[i][j] = (i == j) ? 1.0f : 0.0f;
        }
        __syncthreads();
    }

    if (tid < 264) {                 // stage initial pivot rows 0..3
        int r = tid / 66, g = tid % 66;
        *(float4*)&Praw[0][r][g * 4] = *(const float4*)&C[r][g * 4];
    }
    __syncthreads();

#pragma unroll 1
    for (int kb = 0; kb < 128; kb += 4) {
        const int buf = (kb >> 2) & 1;
        const float* P0 = Praw[buf][0];
        const float* P1 = Praw[buf][1];
        const float* P2 = Praw[buf][2];
        const float* P3 = Praw[buf][3];

        float M00 = P0[128 + kb + 0], M01 = P0[128 + kb + 1], M02 = P0[128 + kb + 2], M03 = P0[128 + kb + 3];
        float M10 = P1[128 + kb + 0], M11 = P1[128 + kb + 1], M12 = P1[128 + kb + 2], M13 = P1[128 + kb + 3];
        float M20 = P2[128 + kb + 0], M21 = P2[128 + kb + 1], M22 = P2[128 + kb + 2], M23 = P2[128 + kb + 3];
        float M30 = P3[128 + kb + 0], M31 = P3[128 + kb + 1], M32 = P3[128 + kb + 2], M33 = P3[128 + kb + 3];

        float rd0 = 1.0f / M00;
        float g10 = M10 * rd0, g20 = M20 * rd0, g30 = M30 * rd0;
        float N11 = M11 - g10 * M01, N12 = M12 - g10 * M02, N13 = M13 - g10 * M03;
        float N21 = M21 - g20 * M01, N22 = M22 - g20 * M02, N23 = M23 - g20 * M03;
        float N31 = M31 - g30 * M01, N32 = M32 - g30 * M02, N33 = M33 - g30 * M03;
        float rd1 = 1.0f / N11;
        float g21 = N21 * rd1, g31 = N31 * rd1;
        float P22 = N22 - g21 * N12, P23 = N23 - g21 * N13;
        float P32 = N32 - g31 * N12, P33 = N33 - g31 * N13;
        float rd2 = 1.0f / P22;
        float g32 = P32 * rd2;
        float Q33 = P33 - g32 * P23;
        float rd3 = 1.0f / Q33;

        float T10 = -g10;
        float T20 = -g20 - g21 * T10, T21 = -g21;
        float T30 = -g30 - g31 * T10 - g32 * T20;
        float T31 = -g31 - g32 * T21;
        float T32 = -g32;

        if (tid == 0) {
            dsq[kb + 0] = 1.0f / sqrtf(M00);
            dsq[kb + 1] = 1.0f / sqrtf(N11);
            dsq[kb + 2] = 1.0f / sqrtf(P22);
            dsq[kb + 3] = 1.0f / sqrtf(Q33);
        }

        const int gs = kb >> 2;
        const bool doB = (cs <= gs);
        const int gRel = gs + 1 + cs;           // A-region group index
        const bool doA = (gRel < 32);

        float4 Pb0, Pb1, Pb2, Pb3, Pa0, Pa1, Pa2, Pa3;
        if (doB) {
            Pb0 = *(const float4*)&P0[cs * 4];
            Pb1 = *(const float4*)&P1[cs * 4];
            Pb2 = *(const float4*)&P2[cs * 4];
            Pb3 = *(const float4*)&P3[cs * 4];
        }
        if (doA) {
            Pa0 = *(const float4*)&P0[128 + gRel * 4];
            Pa1 = *(const float4*)&P1[128 + gRel * 4];
            Pa2 = *(const float4*)&P2[128 + gRel * 4];
            Pa3 = *(const float4*)&P3[128 + gRel * 4];
        }

        const int j0 = kb + 1 + rs;
        const int j1 = j0 + 32, j2 = j0 + 64, j3 = j0 + 96;
        const bool v0 = (j0 < 128), v1 = (j1 < 128), v2 = (j2 < 128), v3 = (j3 < 128);
        const int ja0 = v0 ? j0 : 127, ja1 = v1 ? j1 : 127;
        const int ja2 = v2 ? j2 : 127, ja3 = v3 ? j3 : 127;

        float4 q0 = *(const float4*)&C[ja0][128 + kb];
        float4 q1 = *(const float4*)&C[ja1][128 + kb];
        float4 q2 = *(const float4*)&C[ja2][128 + kb];
        float4 q3 = *(const float4*)&C[ja3][128 + kb];

        float c00, c01 = 0.f, c02 = 0.f, c03 = 0.f;
        {
            const int tmax = 1 + rs;
            float f0 = q0.x * rd0;
            c00 = f0;
            if (tmax > 1) {
                float f1 = (q0.y - c00 * M01) * rd1;
                c00 += f1 * T10; c01 = f1;
                if (tmax > 2) {
                    float f2 = (q0.z - c00 * M02 - c01 * M12) * rd2;
                    c00 += f2 * T20; c01 += f2 * T21; c02 = f2;
                    if (tmax > 3) {
                        float f3 = (q0.w - c00 * M03 - c01 * M13 - c02 * M23) * rd3;
                        c00 += f3 * T30; c01 += f3 * T31; c02 += f3 * T32; c03 = f3;
                    }
                }
            }
        }
#define CHAINF(q, d0, d1, d2, d3) \
        float d0, d1, d2, d3; { \
            float f0 = q.x * rd0; d0 = f0; \
            float f1 = (q.y - d0 * M01) * rd1; d0 += f1 * T10; d1 = f1; \
            float f2 = (q.z - d0 * M02 - d1 * M12) * rd2; \
            d0 += f2 * T20; d1 += f2 * T21; d2 = f2; \
            float f3 = (q.w - d0 * M03 - d1 * M13 - d2 * M23) * rd3; \
            d0 += f3 * T30; d1 += f3 * T31; d2 += f3 * T32; d3 = f3; }
        CHAINF(q1, c10, c11, c12, c13)
        CHAINF(q2, c20, c21, c22, c23)
        CHAINF(q3, c30, c31, c32, c33)
#undef CHAINF

#define UPDATE(jv, jj, e0, e1, e2, e3, STG) do {                              \
        if (jv) {                                                             \
            if (doB) {                                                        \
                float4 v = *(const float4*)&C[jj][cs * 4];                    \
                v.x -= e0 * Pb0.x + e1 * Pb1.x + e2 * Pb2.x + e3 * Pb3.x;     \
                v.y -= e0 * Pb0.y + e1 * Pb1.y + e2 * Pb2.y + e3 * Pb3.y;     \
                v.z -= e0 * Pb0.z + e1 * Pb1.z + e2 * Pb2.z + e3 * Pb3.z;     \
                v.w -= e0 * Pb0.w + e1 * Pb1.w + e2 * Pb2.w + e3 * Pb3.w;     \
                *(float4*)&C[jj][cs * 4] = v;                                 \
                if (STG) *(float4*)&Praw[buf ^ 1][jj - kb - 4][cs * 4] = v;   \
            }                                                                 \
            if (doA) {                                                        \
                float4 v = *(const float4*)&C[jj][128 + gRel * 4];            \
                v.x -= e0 * Pa0.x + e1 * Pa1.x + e2 * Pa2.x + e3 * Pa3.x;     \
                v.y -= e0 * Pa0.y + e1 * Pa1.y + e2 * Pa2.y + e3 * Pa3.y;     \
                v.z -= e0 * Pa0.z + e1 * Pa1.z + e2 * Pa2.z + e3 * Pa3.z;     \
                v.w -= e0 * Pa0.w + e1 * Pa1.w + e2 * Pa2.w + e3 * Pa3.w;     \
                *(float4*)&C[jj][128 + gRel * 4] = v;                         \
                if (STG) *(float4*)&Praw[buf ^ 1][jj - kb - 4][128 + gRel * 4] = v; \
            }                                                                 \
        }                                                                     \
} while (0)

        const bool stage0 = v0 && (j0 >= kb + 4) && (j0 < kb + 8);
        UPDATE(v0, j0, c00, c01, c02, c03, stage0);
        UPDATE(v1, j1, c10, c11, c12, c13, false);
        UPDATE(v2, j2, c20, c21, c22, c23, false);
        UPDATE(v3, j3, c30, c31, c32, c33, false);
#undef UPDATE

        if (tid < 4 && kb + 4 < 128) {
            float4 e = {0.f, 0.f, 0.f, 0.f};
            ((float*)&e)[tid] = 1.0f;
            *(float4*)&Praw[buf ^ 1][tid][(gs + 1) * 4] = e;
        }
        __syncthreads();
    }

    for (int idx = tid; idx < 128 * 128; idx += 1024) {
        int j = idx >> 7, c = idx & 127;
        float vv = (c < j) ? C[j][c] * dsq[j] : ((c == j) ? dsq[j] : 0.0f);
        Wout[idx] = vv;
    }
}

// ---------------------------------------------------------------------------
// k_apply: out = bf16(xn) @ bf16(W)^T.  PRE=1: xn-bf16 precomputed pre-
// swizzled in xbf -> stage is a straight 32KB copy.  PRE=0: legacy path.
// ---------------------------------------------------------------------------
template <int PRE>
__global__ __launch_bounds__(256, 3) void k_apply(const float* __restrict__ x,
                                                  const unsigned short* __restrict__ xbf,
                                                  const float* __restrict__ Wg,
                                                  const float* __restrict__ mg,
                                                  float* __restrict__ out) {
    __shared__ __align__(16) unsigned char XS[128 * 256];   // 128 rows x 128 bf16
    __shared__ float msh[128];
    const int tid = threadIdx.x;
    const int w = tid >> 6, l = tid & 63;
    const int lc = l & 15, la = l >> 4;

    if (!PRE) {
        if (tid < 32) *(float4*)&msh[tid * 4] = *(const float4*)&mg[tid * 4];
        __syncthreads();
    }

    bf16x8 wfrag[2][4];
#pragma unroll
    for (int tjl = 0; tjl < 2; ++tjl) {
        int j = (w * 2 + tjl) * 16 + lc;
#pragma unroll
        for (int ks = 0; ks < 4; ++ks) {
            int i0 = ks * 32 + la * 8;
            float4 wa = *(const float4*)&Wg[j * 128 + i0];
            float4 wb = *(const float4*)&Wg[j * 128 + i0 + 4];
            wfrag[tjl][ks][0] = f2bf_rne(wa.x);
            wfrag[tjl][ks][1] = f2bf_rne(wa.y);
            wfrag[tjl][ks][2] = f2bf_rne(wa.z);
            wfrag[tjl][ks][3] = f2bf_rne(wa.w);
            wfrag[tjl][ks][4] = f2bf_rne(wb.x);
            wfrag[tjl][ks][5] = f2bf_rne(wb.y);
            wfrag[tjl][ks][6] = f2bf_rne(wb.z);
            wfrag[tjl][ks][7] = f2bf_rne(wb.w);
        }
    }

    f32x4 acc[8][2];
#pragma unroll
    for (int ti = 0; ti < 8; ++ti)
#pragma unroll
        for (int tjl = 0; tjl < 2; ++tjl) acc[ti][tjl] = (f32x4){0.f, 0.f, 0.f, 0.f};

    const size_t rowbase = (size_t)blockIdx.x * 128;

    if (PRE) {
        const uint4* src = (const uint4*)(xbf + (size_t)blockIdx.x * 16384);
        uint4* XS4 = (uint4*)XS;
#pragma unroll
        for (int rep = 0; rep < 8; ++rep)
            XS4[tid + 256 * rep] = src[tid + 256 * rep];
    } else {
#pragma unroll
        for (int rep = 0; rep < 16; ++rep) {
            int f = tid + 256 * rep;
            int r = f >> 5, i4 = f & 31;
            float4 vx = *(const float4*)&x[(rowbase + r) * 128 + i4 * 4];
            float4 mv = *(const float4*)&msh[i4 * 4];
            unsigned b0 = f2bf_rne(vx.x - mv.x);
            unsigned b1 = f2bf_rne(vx.y - mv.y);
            unsigned b2 = f2bf_rne(vx.z - mv.z);
            unsigned b3 = f2bf_rne(vx.w - mv.w);
            int g = i4 >> 1, half = i4 & 1;
            unsigned off = r * 256 + ((g ^ (r & 15)) << 4) + half * 8;
            *(uint2*)(XS + off) = make_uint2(b0 | (b1 << 16), b2 | (b3 << 16));
        }
    }
    __syncthreads();

#pragma unroll
    for (int ks = 0; ks < 4; ++ks) {
#pragma unroll
        for (int ti = 0; ti < 8; ++ti) {
            int r = ti * 16 + lc;
            int g = ks * 4 + la;
            bf16x8 af = *(const bf16x8*)(XS + r * 256 + (((g ^ (r & 15))) << 4));
            acc[ti][0] = __builtin_amdgcn_mfma_f32_16x16x32_bf16(af, wfrag[0][ks], acc[ti][0], 0, 0, 0);
            acc[ti][1] = __builtin_amdgcn_mfma_f32_16x16x32_bf16(af, wfrag[1][ks], acc[ti][1], 0, 0, 0);
        }
    }

    float* dst = out + rowbase * 128;
#pragma unroll
    for (int ti = 0; ti < 8; ++ti)
#pragma unroll
        for (int tjl = 0; tjl < 2; ++tjl)
#pragma unroll
            for (int q = 0; q < 4; ++q) {
                int rloc = ti * 16 + la * 4 + q;
                int cglob = (w * 2 + tjl) * 16 + lc;
                dst[rloc * 128 + cglob] = acc[ti][tjl][q];
            }
}

extern "C" void kernel_launch(void* const* d_in, const int* in_sizes, int n_in,
                              void* d_out, int out_size, void* d_ws, size_t ws_size,
                              hipStream_t stream) {
    const float* x = (const float*)d_in[0];
    float* ws = (float*)d_ws;
    float* gram = ws;                  // 16384
    float* colsum = ws + 16384;        // 128
    float* W = ws + 16512;             // 16384
    float* m = ws + 32896;             // 128
    float* colpart = ws + 40960;       // up to 1024*128
    float* part = ws + 172032;         // nP*16384
    float* out = (float*)d_out;

    const size_t XBF_FLOATS = (size_t)NROWS * NCH / 2;   // 128MB of bf16
    int nP = 0;
    for (int cand = 1024; cand >= 256; cand >>= 1) {
        int ng = cand / 32;
        size_t need = ((size_t)172032 + (size_t)cand * 16384 +
                       (size_t)ng * 16384 + (size_t)ng * 128 + XBF_FLOATS) * sizeof(float);
        if (ws_size >= need) { nP = cand; break; }
    }

    if (nP > 0) {
        const int NG = nP / 32;
        float* part2 = part + (size_t)nP * 16384;
        float* col2 = part2 + (size_t)NG * 16384;
        unsigned short* xbf = (unsigned short*)(col2 + (size_t)NG * 128);
        int cpb = 16384 / nP;
        k_gram<1><<<nP, 256, 0, stream>>>(x, part, colpart, gram, colsum, cpb);
        k_reduce1<<<16 * NG + NG, 256, 0, stream>>>(part, colpart, part2, col2, NG);
        // block 0: stage-2 fold + Cholesky+inverse; blocks 1..255: fold col2
        // + convert x -> swizzled bf16 xn tiles, all under chol's shadow.
        k_chol<<<256, 1024, 0, stream>>>(part2, col2, gram, colsum, W, m, x, xbf, NG);
        k_apply<1><<<NROWS / 128, 256, 0, stream>>>(x, xbf, W, m, out);
    } else {
        hipMemsetAsync(d_ws, 0, (16384 + 128) * sizeof(float), stream);
        k_gram<0><<<512, 256, 0, stream>>>(x, part, colpart, gram, colsum, 32);
        k_chol<<<1, 1024, 0, stream>>>(nullptr, nullptr, gram, colsum, W, m, x, nullptr, 0);
        k_apply<0><<<NROWS / 128, 256, 0, stream>>>(x, nullptr, W, m, out);
    }
}

// Round 19
// 269.933 us; speedup vs baseline: 1.1128x; 1.1128x over previous
//
#include <hip/hip_runtime.h>

#define NROWS 524288
#define NCH 128
#define GSTR 40

typedef __attribute__((ext_vector_type(8))) short bf16x8;
typedef __attribute__((ext_vector_type(4))) float f32x4;

// barrier WITHOUT vmcnt drain: LDS ordering only (T4-lite).
#define BARRIER_ND() asm volatile("s_waitcnt lgkmcnt(0)\ns_barrier" ::: "memory")

static __device__ __forceinline__ unsigned short f2bf_rne(float f) {
    unsigned u = __float_as_uint(f);
    return (unsigned short)((u + 0x7FFFu + ((u >> 16) & 1u)) >> 16);
}

// Channel row layout: data starts at ((c>>3)&1)*8 u16 within the 40-u16 row
// (pad as bank-offset: 32 distinct write banks across wave64 = 2-way = free).
static __device__ __forceinline__ bf16x8 ldfrag(const unsigned short* base, int c, int s0) {
    int m = (c >> 3) & 12;
    return *(const bf16x8*)(base + c * GSTR + (((c >> 3) & 1) << 3) + 2 * (s0 ^ m));
}

// ---------------------------------------------------------------------------
// k_gram (R15-proven): G2 = H^T H + H^T (2L); (256,4); no-drain barriers.
// ---------------------------------------------------------------------------
#define PACKW1(B, c, x0, x1, csacc) do {                                      \
    unsigned u0 = __float_as_uint(x0), u1 = __float_as_uint(x1);              \
    unsigned packH = (u0 >> 16) | (u1 & 0xFFFF0000u);                         \
    float l0_ = 2.0f * ((x0) - __uint_as_float(u0 & 0xFFFF0000u));            \
    float l1_ = 2.0f * ((x1) - __uint_as_float(u1 & 0xFFFF0000u));            \
    unsigned packL = (unsigned)f2bf_rne(l0_) | ((unsigned)f2bf_rne(l1_) << 16); \
    int idx_ = (c) * GSTR + ((cg & 1) << 3) + 2 * (p ^ (cg & 12));            \
    *(unsigned*)&XT[B][0][idx_] = packH;                                      \
    *(unsigned*)&XT[B][1][idx_] = packL;                                      \
    csacc += (x0) + (x1);                                                     \
} while (0)

#define LOADR(ci, r0, r1, r2, r3) do {                                        \
    const float4* s4_ = (const float4*)x + ((size_t)(ci) * 32 + 2 * p) * 32 + cg * 2; \
    r0 = s4_[0]; r1 = s4_[1]; r2 = s4_[32]; r3 = s4_[33];                     \
} while (0)

#define PACKALL(B, r0, r1, r2, r3) do {                                       \
    PACKW1(B, cg * 8 + 0, r0.x, r2.x, cs0);                                   \
    PACKW1(B, cg * 8 + 1, r0.y, r2.y, cs1);                                   \
    PACKW1(B, cg * 8 + 2, r0.z, r2.z, cs2);                                   \
    PACKW1(B, cg * 8 + 3, r0.w, r2.w, cs3);                                   \
    PACKW1(B, cg * 8 + 4, r1.x, r3.x, cs4);                                   \
    PACKW1(B, cg * 8 + 5, r1.y, r3.y, cs5);                                   \
    PACKW1(B, cg * 8 + 6, r1.z, r3.z, cs6);                                   \
    PACKW1(B, cg * 8 + 7, r1.w, r3.w, cs7);                                   \
} while (0)

#define MFMA_STEP(B) do {                                                     \
    const unsigned short* Xh = &XT[B][0][0];                                  \
    const unsigned short* Xl = &XT[B][1][0];                                  \
    bf16x8 ah0 = ldfrag(Xh, (2 * w + 0) * 16 + lc, ls);                       \
    bf16x8 ah1 = ldfrag(Xh, (2 * w + 1) * 16 + lc, ls);                       \
    _Pragma("unroll")                                                         \
    for (int tj = 0; tj < 8; ++tj) {                                          \
        bf16x8 bh = ldfrag(Xh, tj * 16 + lc, ls);                             \
        bf16x8 bl = ldfrag(Xl, tj * 16 + lc, ls);                             \
        acc[0][tj] = __builtin_amdgcn_mfma_f32_16x16x32_bf16(ah0, bh, acc[0][tj], 0, 0, 0); \
        acc[0][tj] = __builtin_amdgcn_mfma_f32_16x16x32_bf16(ah0, bl, acc[0][tj], 0, 0, 0); \
        acc[1][tj] = __builtin_amdgcn_mfma_f32_16x16x32_bf16(ah1, bh, acc[1][tj], 0, 0, 0); \
        acc[1][tj] = __builtin_amdgcn_mfma_f32_16x16x32_bf16(ah1, bl, acc[1][tj], 0, 0, 0); \
    }                                                                         \
} while (0)

template <int STORE>
__global__ __launch_bounds__(256, 4) void k_gram(const float* __restrict__ x,
                                                 float* __restrict__ part,
                                                 float* __restrict__ colpart,
                                                 float* __restrict__ gram,
                                                 float* __restrict__ colsum,
                                                 int cpb) {
    __shared__ __align__(16) unsigned short XT[2][2][128 * GSTR];  // [buf][hi/lo]
    const int tid = threadIdx.x;
    const int w = tid >> 6;
    const int l = tid & 63;
    const int lc = l & 15;
    const int ls = (l >> 4) * 4;
    const int p = tid >> 4;          // row-pair (rows 2p,2p+1 of chunk)
    const int cg = tid & 15;         // channel-group (8 ch), lane-minor

    f32x4 acc[2][8];
#pragma unroll
    for (int a = 0; a < 2; ++a)
#pragma unroll
        for (int t = 0; t < 8; ++t) acc[a][t] = (f32x4){0.f, 0.f, 0.f, 0.f};
    float cs0 = 0.f, cs1 = 0.f, cs2 = 0.f, cs3 = 0.f;
    float cs4 = 0.f, cs5 = 0.f, cs6 = 0.f, cs7 = 0.f;

    const int c0 = blockIdx.x * cpb;
    float4 a0, a1, a2, a3, b0, b1, b2, b3;

    LOADR(c0 + 0, a0, a1, a2, a3);
    LOADR(c0 + 1, b0, b1, b2, b3);
    PACKALL(0, a0, a1, a2, a3);
    BARRIER_ND();

#pragma unroll 1
    for (int t = 0; t < cpb; t += 2) {
        MFMA_STEP(0);                         // chunk t
        PACKALL(1, b0, b1, b2, b3);           // chunk t+1 -> LDS[1]
        if (t + 2 < cpb) LOADR(c0 + t + 2, a0, a1, a2, a3);
        BARRIER_ND();
        MFMA_STEP(1);                         // chunk t+1
        if (t + 2 < cpb) {
            PACKALL(0, a0, a1, a2, a3);       // chunk t+2 -> LDS[0]
            if (t + 3 < cpb) LOADR(c0 + t + 3, b0, b1, b2, b3);
            BARRIER_ND();
        }
    }

    // intra-block colsum reduction (reuse XT as float LDS)
    __syncthreads();
    float* cls = (float*)&XT[0][0][0];        // 128 ch x 16 pairs
    cls[(cg * 8 + 0) * 16 + p] = cs0;
    cls[(cg * 8 + 1) * 16 + p] = cs1;
    cls[(cg * 8 + 2) * 16 + p] = cs2;
    cls[(cg * 8 + 3) * 16 + p] = cs3;
    cls[(cg * 8 + 4) * 16 + p] = cs4;
    cls[(cg * 8 + 5) * 16 + p] = cs5;
    cls[(cg * 8 + 6) * 16 + p] = cs6;
    cls[(cg * 8 + 7) * 16 + p] = cs7;
    __syncthreads();
    float csr = 0.f;
    if (tid < 128) {
#pragma unroll
        for (int pp = 0; pp < 16; ++pp) csr += cls[tid * 16 + pp];
    }

    if (STORE) {
        float* pb = part + (size_t)blockIdx.x * 16384;
#pragma unroll
        for (int a = 0; a < 2; ++a)
#pragma unroll
            for (int tj = 0; tj < 8; ++tj)
#pragma unroll
                for (int q = 0; q < 4; ++q) {
                    int row = (2 * w + a) * 16 + (l >> 4) * 4 + q;
                    int col = tj * 16 + lc;
                    pb[row * NCH + col] = acc[a][tj][q];
                }
        if (tid < 128) colpart[blockIdx.x * 128 + tid] = csr;
    } else {
#pragma unroll
        for (int a = 0; a < 2; ++a)
#pragma unroll
            for (int tj = 0; tj < 8; ++tj)
#pragma unroll
                for (int q = 0; q < 4; ++q) {
                    int row = (2 * w + a) * 16 + (l >> 4) * 4 + q;
                    int col = tj * 16 + lc;
                    atomicAdd(&gram[row * NCH + col], acc[a][tj][q]);
                }
        if (tid < 128) atomicAdd(&colsum[tid], csr);
    }
}

// ---------------------------------------------------------------------------
// Two-stage tree reduction of per-block partials (R7-proven).
// ---------------------------------------------------------------------------
__global__ __launch_bounds__(256) void k_reduce1(const float* __restrict__ part,
                                                 const float* __restrict__ colpart,
                                                 float* __restrict__ part2,
                                                 float* __restrict__ col2,
                                                 int NG) {
    const int b = blockIdx.x;
    if (b < 16 * NG) {
        const int g = b >> 4;
        const int sl = b & 15;
        const int e4 = sl * 1024 + threadIdx.x * 4;
        const float* p0 = part + (size_t)g * 32 * 16384 + e4;
        float4 s = {0.f, 0.f, 0.f, 0.f};
#pragma unroll
        for (int k = 0; k < 32; ++k) {
            float4 v = *(const float4*)(p0 + (size_t)k * 16384);
            s.x += v.x; s.y += v.y; s.z += v.z; s.w += v.w;
        }
        *(float4*)(part2 + (size_t)g * 16384 + e4) = s;
    } else {
        const int g = b - 16 * NG;
        if (threadIdx.x < 128) {
            const float* c0 = colpart + g * 32 * 128 + threadIdx.x;
            float s = 0.f;
#pragma unroll
            for (int k = 0; k < 32; ++k) s += c0[k * 128];
            col2[g * 128 + threadIdx.x] = s;
        }
    }
}

__global__ __launch_bounds__(256) void k_reduce2(const float* __restrict__ part2,
                                                 const float* __restrict__ col2,
                                                 float* __restrict__ gram,
                                                 float* __restrict__ colsum,
                                                 int NG) {
    const int b = blockIdx.x;
    if (b < 16) {
        const int e4 = b * 1024 + threadIdx.x * 4;
        float4 s = {0.f, 0.f, 0.f, 0.f};
#pragma unroll 8
        for (int g = 0; g < NG; ++g) {
            float4 v = *(const float4*)(part2 + (size_t)g * 16384 + e4);
            s.x += v.x; s.y += v.y; s.z += v.z; s.w += v.w;
        }
        *(float4*)(gram + e4) = s;
    } else if (threadIdx.x < 128) {
        float s = 0.f;
#pragma unroll 8
        for (int g = 0; g < NG; ++g) s += col2[g * 128 + threadIdx.x];
        colsum[threadIdx.x] = s;
    }
}

// ---------------------------------------------------------------------------
// k_chol: block 0 = 4-pivot blocked Gauss-Jordan (R14 logic).  Blocks
// 1..255 = convert x -> bf16(x - m) pre-swizzled into apply's tile layout
// (xbf) under chol's shadow.  Stream order guarantees xbf before k_apply.
// ---------------------------------------------------------------------------
__global__ __launch_bounds__(1024) void k_chol(const float* __restrict__ gram,
                                               const float* __restrict__ colsum,
                                               float* __restrict__ Wout,
                                               float* __restrict__ mout,
                                               const float* __restrict__ x,
                                               unsigned short* __restrict__ xbf) {
    if (blockIdx.x != 0) {
        __shared__ float msh[128];
        if (threadIdx.x < 32) {
            float4 cv = ((const float4*)colsum)[threadIdx.x];
            const float sc = 1.0f / (float)NROWS;
            cv.x *= sc; cv.y *= sc; cv.z *= sc; cv.w *= sc;
            *(float4*)&msh[threadIdx.x * 4] = cv;
        }
        __syncthreads();
        const size_t stride = (size_t)(gridDim.x - 1) * 1024;
        const size_t total = (size_t)(NROWS / 128) * 4096;   // 16.8M fragments
        for (size_t f = (size_t)(blockIdx.x - 1) * 1024 + threadIdx.x; f < total; f += stride) {
            int tile = (int)(f >> 12);
            int within = (int)(f & 4095);
            int r = within >> 5, i4 = within & 31;
            float4 vx = *(const float4*)&x[((size_t)tile * 128 + r) * 128 + i4 * 4];
            float4 mv = *(const float4*)&msh[i4 * 4];
            unsigned b0 = f2bf_rne(vx.x - mv.x);
            unsigned b1 = f2bf_rne(vx.y - mv.y);
            unsigned b2 = f2bf_rne(vx.z - mv.z);
            unsigned b3 = f2bf_rne(vx.w - mv.w);
            size_t d8 = (size_t)tile * 4096 + r * 32 + (((i4 >> 1) ^ (r & 15)) << 1) + (i4 & 1);
            ((uint2*)xbf)[d8] = make_uint2(b0 | (b1 << 16), b2 | (b3 << 16));
        }
        return;
    }

    __shared__ float C[128][264];                    // [0..127]=B, [128..255]=A
    __shared__ __align__(16) float Praw[2][4][264];  // double-buffered raw pivot rows
    __shared__ float m[128];
    __shared__ float dsq[128];
    const int tid = threadIdx.x;
    const int rs = tid >> 5;        // rowslot 0..31
    const int cs = tid & 31;        // colslot 0..31

    if (tid < 128) {
        m[tid] = colsum[tid] * (1.0f / (float)NROWS);
        mout[tid] = m[tid];
    }
    __syncthreads();
    for (int idx = tid; idx < 128 * 128; idx += 1024) {
        int i = idx >> 7, j = idx & 127;
        float g = 0.5f * (gram[i * NCH + j] + gram[j * NCH + i]);   // sym(G2)
        C[i][128 + j] = (g - (float)NROWS * m[i] * m[j]) * (1.0f / (float)(NROWS - 1));
        C[i][j] = (i == j) ? 1.0f : 0.0f;
    }
    __syncthreads();
    if (tid < 264) {                 // stage initial pivot rows 0..3
        int r = tid / 66, g = tid % 66;
        *(float4*)&Praw[0][r][g * 4] = *(const float4*)&C[r][g * 4];
    }
    __syncthreads();

#pragma unroll 1
    for (int kb = 0; kb < 128; kb += 4) {
        const int buf = (kb >> 2) & 1;
        const float* P0 = Praw[buf][0];
        const float* P1 = Praw[buf][1];
        const float* P2 = Praw[buf][2];
        const float* P3 = Praw[buf][3];

        float M00 = P0[128 + kb + 0], M01 = P0[128 + kb + 1], M02 = P0[128 + kb + 2], M03 = P0[128 + kb + 3];
        float M10 = P1[128 + kb + 0], M11 = P1[128 + kb + 1], M12 = P1[128 + kb + 2], M13 = P1[128 + kb + 3];
        float M20 = P2[128 + kb + 0], M21 = P2[128 + kb + 1], M22 = P2[128 + kb + 2], M23 = P2[128 + kb + 3];
        float M30 = P3[128 + kb + 0], M31 = P3[128 + kb + 1], M32 = P3[128 + kb + 2], M33 = P3[128 + kb + 3];

        float rd0 = 1.0f / M00;
        float g10 = M10 * rd0, g20 = M20 * rd0, g30 = M30 * rd0;
        float N11 = M11 - g10 * M01, N12 = M12 - g10 * M02, N13 = M13 - g10 * M03;
        float N21 = M21 - g20 * M01, N22 = M22 - g20 * M02, N23 = M23 - g20 * M03;
        float N31 = M31 - g30 * M01, N32 = M32 - g30 * M02, N33 = M33 - g30 * M03;
        float rd1 = 1.0f / N11;
        float g21 = N21 * rd1, g31 = N31 * rd1;
        float P22 = N22 - g21 * N12, P23 = N23 - g21 * N13;
        float P32 = N32 - g31 * N12, P33 = N33 - g31 * N13;
        float rd2 = 1.0f / P22;
        float g32 = P32 * rd2;
        float Q33 = P33 - g32 * P23;
        float rd3 = 1.0f / Q33;

        float T10 = -g10;
        float T20 = -g20 - g21 * T10, T21 = -g21;
        float T30 = -g30 - g31 * T10 - g32 * T20;
        float T31 = -g31 - g32 * T21;
        float T32 = -g32;

        if (tid == 0) {
            dsq[kb + 0] = 1.0f / sqrtf(M00);
            dsq[kb + 1] = 1.0f / sqrtf(N11);
            dsq[kb + 2] = 1.0f / sqrtf(P22);
            dsq[kb + 3] = 1.0f / sqrtf(Q33);
        }

        const int gs = kb >> 2;
        const bool doB = (cs <= gs);
        const int gRel = gs + 1 + cs;           // A-region group index
        const bool doA = (gRel < 32);

        float4 Pb0, Pb1, Pb2, Pb3, Pa0, Pa1, Pa2, Pa3;
        if (doB) {
            Pb0 = *(const float4*)&P0[cs * 4];
            Pb1 = *(const float4*)&P1[cs * 4];
            Pb2 = *(const float4*)&P2[cs * 4];
            Pb3 = *(const float4*)&P3[cs * 4];
        }
        if (doA) {
            Pa0 = *(const float4*)&P0[128 + gRel * 4];
            Pa1 = *(const float4*)&P1[128 + gRel * 4];
            Pa2 = *(const float4*)&P2[128 + gRel * 4];
            Pa3 = *(const float4*)&P3[128 + gRel * 4];
        }

        const int j0 = kb + 1 + rs;
        const int j1 = j0 + 32, j2 = j0 + 64, j3 = j0 + 96;
        const bool v0 = (j0 < 128), v1 = (j1 < 128), v2 = (j2 < 128), v3 = (j3 < 128);
        const int ja0 = v0 ? j0 : 127, ja1 = v1 ? j1 : 127;
        const int ja2 = v2 ? j2 : 127, ja3 = v3 ? j3 : 127;

        float4 q0 = *(const float4*)&C[ja0][128 + kb];
        float4 q1 = *(const float4*)&C[ja1][128 + kb];
        float4 q2 = *(const float4*)&C[ja2][128 + kb];
        float4 q3 = *(const float4*)&C[ja3][128 + kb];

        float c00, c01 = 0.f, c02 = 0.f, c03 = 0.f;
        {
            const int tmax = 1 + rs;
            float f0 = q0.x * rd0;
            c00 = f0;
            if (tmax > 1) {
                float f1 = (q0.y - c00 * M01) * rd1;
                c00 += f1 * T10; c01 = f1;
                if (tmax > 2) {
                    float f2 = (q0.z - c00 * M02 - c01 * M12) * rd2;
                    c00 += f2 * T20; c01 += f2 * T21; c02 = f2;
                    if (tmax > 3) {
                        float f3 = (q0.w - c00 * M03 - c01 * M13 - c02 * M23) * rd3;
                        c00 += f3 * T30; c01 += f3 * T31; c02 += f3 * T32; c03 = f3;
                    }
                }
            }
        }
#define CHAINF(q, d0, d1, d2, d3) \
        float d0, d1, d2, d3; { \
            float f0 = q.x * rd0; d0 = f0; \
            float f1 = (q.y - d0 * M01) * rd1; d0 += f1 * T10; d1 = f1; \
            float f2 = (q.z - d0 * M02 - d1 * M12) * rd2; \
            d0 += f2 * T20; d1 += f2 * T21; d2 = f2; \
            float f3 = (q.w - d0 * M03 - d1 * M13 - d2 * M23) * rd3; \
            d0 += f3 * T30; d1 += f3 * T31; d2 += f3 * T32; d3 = f3; }
        CHAINF(q1, c10, c11, c12, c13)
        CHAINF(q2, c20, c21, c22, c23)
        CHAINF(q3, c30, c31, c32, c33)
#undef CHAINF

#define UPDATE(jv, jj, e0, e1, e2, e3, STG) do {                              \
        if (jv) {                                                             \
            if (doB) {                                                        \
                float4 v = *(const float4*)&C[jj][cs * 4];                    \
                v.x -= e0 * Pb0.x + e1 * Pb1.x + e2 * Pb2.x + e3 * Pb3.x;     \
                v.y -= e0 * Pb0.y + e1 * Pb1.y + e2 * Pb2.y + e3 * Pb3.y;     \
                v.z -= e0 * Pb0.z + e1 * Pb1.z + e2 * Pb2.z + e3 * Pb3.z;     \
                v.w -= e0 * Pb0.w + e1 * Pb1.w + e2 * Pb2.w + e3 * Pb3.w;     \
                *(float4*)&C[jj][cs * 4] = v;                                 \
                if (STG) *(float4*)&Praw[buf ^ 1][jj - kb - 4][cs * 4] = v;   \
            }                                                                 \
            if (doA) {                                                        \
                float4 v = *(const float4*)&C[jj][128 + gRel * 4];            \
                v.x -= e0 * Pa0.x + e1 * Pa1.x + e2 * Pa2.x + e3 * Pa3.x;     \
                v.y -= e0 * Pa0.y + e1 * Pa1.y + e2 * Pa2.y + e3 * Pa3.y;     \
                v.z -= e0 * Pa0.z + e1 * Pa1.z + e2 * Pa2.z + e3 * Pa3.z;     \
                v.w -= e0 * Pa0.w + e1 * Pa1.w + e2 * Pa2.w + e3 * Pa3.w;     \
                *(float4*)&C[jj][128 + gRel * 4] = v;                         \
                if (STG) *(float4*)&Praw[buf ^ 1][jj - kb - 4][128 + gRel * 4] = v; \
            }                                                                 \
        }                                                                     \
} while (0)

        const bool stage0 = v0 && (j0 >= kb + 4) && (j0 < kb + 8);
        UPDATE(v0, j0, c00, c01, c02, c03, stage0);
        UPDATE(v1, j1, c10, c11, c12, c13, false);
        UPDATE(v2, j2, c20, c21, c22, c23, false);
        UPDATE(v3, j3, c30, c31, c32, c33, false);
#undef UPDATE

        if (tid < 4 && kb + 4 < 128) {
            float4 e = {0.f, 0.f, 0.f, 0.f};
            ((float*)&e)[tid] = 1.0f;
            *(float4*)&Praw[buf ^ 1][tid][(gs + 1) * 4] = e;
        }
        __syncthreads();
    }

    for (int idx = tid; idx < 128 * 128; idx += 1024) {
        int j = idx >> 7, c = idx & 127;
        float vv = (c < j) ? C[j][c] * dsq[j] : ((c == j) ? dsq[j] : 0.0f);
        Wout[idx] = vv;
    }
}

// ---------------------------------------------------------------------------
// k_apply: out = bf16(xn) @ bf16(W)^T.  PRE=1: xn-bf16 precomputed and
// pre-swizzled in xbf -> stage is a straight 32KB copy (coalesced global
// read, linear conflict-free LDS write).  PRE=0: legacy f32 staging path.
// ---------------------------------------------------------------------------
template <int PRE>
__global__ __launch_bounds__(256, 3) void k_apply(const float* __restrict__ x,
                                                  const unsigned short* __restrict__ xbf,
                                                  const float* __restrict__ Wg,
                                                  const float* __restrict__ mg,
                                                  float* __restrict__ out) {
    __shared__ __align__(16) unsigned char XS[128 * 256];   // 128 rows x 128 bf16
    __shared__ float msh[128];
    const int tid = threadIdx.x;
    const int w = tid >> 6, l = tid & 63;
    const int lc = l & 15, la = l >> 4;

    if (!PRE) {
        if (tid < 32) *(float4*)&msh[tid * 4] = *(const float4*)&mg[tid * 4];
        __syncthreads();
    }

    bf16x8 wfrag[2][4];
#pragma unroll
    for (int tjl = 0; tjl < 2; ++tjl) {
        int j = (w * 2 + tjl) * 16 + lc;
#pragma unroll
        for (int ks = 0; ks < 4; ++ks) {
            int i0 = ks * 32 + la * 8;
            float4 wa = *(const float4*)&Wg[j * 128 + i0];
            float4 wb = *(const float4*)&Wg[j * 128 + i0 + 4];
            wfrag[tjl][ks][0] = f2bf_rne(wa.x);
            wfrag[tjl][ks][1] = f2bf_rne(wa.y);
            wfrag[tjl][ks][2] = f2bf_rne(wa.z);
            wfrag[tjl][ks][3] = f2bf_rne(wa.w);
            wfrag[tjl][ks][4] = f2bf_rne(wb.x);
            wfrag[tjl][ks][5] = f2bf_rne(wb.y);
            wfrag[tjl][ks][6] = f2bf_rne(wb.z);
            wfrag[tjl][ks][7] = f2bf_rne(wb.w);
        }
    }

    f32x4 acc[8][2];
#pragma unroll
    for (int ti = 0; ti < 8; ++ti)
#pragma unroll
        for (int tjl = 0; tjl < 2; ++tjl) acc[ti][tjl] = (f32x4){0.f, 0.f, 0.f, 0.f};

    const size_t rowbase = (size_t)blockIdx.x * 128;

    if (PRE) {
        const uint4* src = (const uint4*)(xbf + (size_t)blockIdx.x * 16384);
        uint4* XS4 = (uint4*)XS;
#pragma unroll
        for (int rep = 0; rep < 8; ++rep)
            XS4[tid + 256 * rep] = src[tid + 256 * rep];
    } else {
#pragma unroll
        for (int rep = 0; rep < 16; ++rep) {
            int f = tid + 256 * rep;
            int r = f >> 5, i4 = f & 31;
            float4 vx = *(const float4*)&x[(rowbase + r) * 128 + i4 * 4];
            float4 mv = *(const float4*)&msh[i4 * 4];
            unsigned b0 = f2bf_rne(vx.x - mv.x);
            unsigned b1 = f2bf_rne(vx.y - mv.y);
            unsigned b2 = f2bf_rne(vx.z - mv.z);
            unsigned b3 = f2bf_rne(vx.w - mv.w);
            int g = i4 >> 1, half = i4 & 1;
            unsigned off = r * 256 + ((g ^ (r & 15)) << 4) + half * 8;
            *(uint2*)(XS + off) = make_uint2(b0 | (b1 << 16), b2 | (b3 << 16));
        }
    }
    __syncthreads();

#pragma unroll
    for (int ks = 0; ks < 4; ++ks) {
#pragma unroll
        for (int ti = 0; ti < 8; ++ti) {
            int r = ti * 16 + lc;
            int g = ks * 4 + la;
            bf16x8 af = *(const bf16x8*)(XS + r * 256 + (((g ^ (r & 15))) << 4));
            acc[ti][0] = __builtin_amdgcn_mfma_f32_16x16x32_bf16(af, wfrag[0][ks], acc[ti][0], 0, 0, 0);
            acc[ti][1] = __builtin_amdgcn_mfma_f32_16x16x32_bf16(af, wfrag[1][ks], acc[ti][1], 0, 0, 0);
        }
    }

    float* dst = out + rowbase * 128;
#pragma unroll
    for (int ti = 0; ti < 8; ++ti)
#pragma unroll
        for (int tjl = 0; tjl < 2; ++tjl)
#pragma unroll
            for (int q = 0; q < 4; ++q) {
                int rloc = ti * 16 + la * 4 + q;
                int cglob = (w * 2 + tjl) * 16 + lc;
                dst[rloc * 128 + cglob] = acc[ti][tjl][q];
            }
}

extern "C" void kernel_launch(void* const* d_in, const int* in_sizes, int n_in,
                              void* d_out, int out_size, void* d_ws, size_t ws_size,
                              hipStream_t stream) {
    const float* x = (const float*)d_in[0];
    float* ws = (float*)d_ws;
    float* gram = ws;                  // 16384
    float* colsum = ws + 16384;        // 128
    float* W = ws + 16512;             // 16384
    float* m = ws + 32896;             // 128
    float* colpart = ws + 40960;       // up to 1024*128
    float* part = ws + 172032;         // nP*16384
    float* out = (float*)d_out;

    const size_t XBF_FLOATS = (size_t)NROWS * NCH / 2;   // 16.8M floats = 128MB bf16
    int nP = 0;
    for (int cand = 1024; cand >= 256; cand >>= 1) {
        int ng = cand / 32;
        size_t need = ((size_t)172032 + (size_t)cand * 16384 +
                       (size_t)ng * 16384 + (size_t)ng * 128 + XBF_FLOATS) * sizeof(float);
        if (ws_size >= need) { nP = cand; break; }
    }

    if (nP > 0) {
        const int NG = nP / 32;
        float* part2 = part + (size_t)nP * 16384;
        float* col2 = part2 + (size_t)NG * 16384;
        unsigned short* xbf = (unsigned short*)(col2 + (size_t)NG * 128);
        int cpb = 16384 / nP;
        k_gram<1><<<nP, 256, 0, stream>>>(x, part, colpart, gram, colsum, cpb);
        k_reduce1<<<16 * NG + NG, 256, 0, stream>>>(part, colpart, part2, col2, NG);
        k_reduce2<<<17, 256, 0, stream>>>(part2, col2, gram, colsum, NG);
        // block 0: Cholesky+inverse; blocks 1..255: convert x -> swizzled bf16
        // xn tiles under chol's shadow.
        k_chol<<<256, 1024, 0, stream>>>(gram, colsum, W, m, x, xbf);
        k_apply<1><<<NROWS / 128, 256, 0, stream>>>(x, xbf, W, m, out);
    } else {
        hipMemsetAsync(d_ws, 0, (16384 + 128) * sizeof(float), stream);
        k_gram<0><<<512, 256, 0, stream>>>(x, part, colpart, gram, colsum, 32);
        k_chol<<<1, 1024, 0, stream>>>(gram, colsum, W, m, x, nullptr);
        k_apply<0><<<NROWS / 128, 256, 0, stream>>>(x, nullptr, W, m, out);
    }
}